// Round 9
// baseline (1267.162 us; speedup 1.0000x reference)
//
#include <hip/hip_runtime.h>

constexpr int NFEAT = 256;
constexpr int NHID  = 128;
constexpr int SCAN_B = 4096;   // elements per scan block (1024 threads x 4)
constexpr int DBINS  = 256;    // degree bins for row pairing sort

// ---------------- CSR build ----------------
// hist captures each edge's within-row rank from the atomicAdd return value;
// scatter then needs NO atomic: p = row_ptr[row] + rank (unique by constr.)

__global__ void hist_kernel(const int* __restrict__ rows, int* __restrict__ cnt,
                            int* __restrict__ rank, int n) {
  int i = blockIdx.x * blockDim.x + threadIdx.x;
  if (i < n) rank[i] = atomicAdd(&cnt[rows[i]], 1);
}

__global__ void scan1_kernel(const int* __restrict__ cnt, int* __restrict__ part,
                             int* __restrict__ bsum, int n) {
  __shared__ int tmp[1024];
  int tid = threadIdx.x;
  int base = blockIdx.x * SCAN_B + tid * 4;
  int4 v = make_int4(0, 0, 0, 0);
  if (base + 4 <= n) {
    v = *(const int4*)&cnt[base];
  } else {
    if (base + 0 < n) v.x = cnt[base + 0];
    if (base + 1 < n) v.y = cnt[base + 1];
    if (base + 2 < n) v.z = cnt[base + 2];
    if (base + 3 < n) v.w = cnt[base + 3];
  }
  int s = v.x + v.y + v.z + v.w;
  tmp[tid] = s;
  __syncthreads();
  for (int off = 1; off < 1024; off <<= 1) {
    int t = (tid >= off) ? tmp[tid - off] : 0;
    __syncthreads();
    tmp[tid] += t;
    __syncthreads();
  }
  int excl = tmp[tid] - s;
  if (base + 0 < n) part[base + 0] = excl;
  if (base + 1 < n) part[base + 1] = excl + v.x;
  if (base + 2 < n) part[base + 2] = excl + v.x + v.y;
  if (base + 3 < n) part[base + 3] = excl + v.x + v.y + v.z;
  if (tid == 1023) bsum[blockIdx.x] = tmp[1023];
}

__global__ void scan2_kernel(int* __restrict__ bsum, int nb) {
  if (threadIdx.x == 0 && blockIdx.x == 0) {
    int run = 0;
    for (int i = 0; i < nb; ++i) { int t = bsum[i]; bsum[i] = run; run += t; }
    bsum[nb] = run;
  }
}

__global__ void scan3_kernel(int* __restrict__ row_ptr, const int* __restrict__ bsum,
                             int n, int nb) {
  int i = blockIdx.x * blockDim.x + threadIdx.x;
  if (i < n) row_ptr[i] += bsum[i / SCAN_B];
  if (i == 0) row_ptr[n] = bsum[nb];
}

__global__ void scatter_kernel(const int* __restrict__ rows, const int* __restrict__ cols,
                               const float* __restrict__ vals, const int* __restrict__ rank,
                               const int* __restrict__ row_ptr, int2* __restrict__ ev_s, int n) {
  int i = blockIdx.x * blockDim.x + threadIdx.x;
  if (i < n) {
    int p = row_ptr[rows[i]] + rank[i];
    ev_s[p] = make_int2(cols[i], __float_as_int(vals[i]));
  }
}

// ---- degree-sorted row permutation (pairs equal-degree rows per wave) ----
// output is bitwise-identical for any perm: each row's edge list & sum order
// are untouched; perm only reassigns rows to waves.

__global__ void deg_hist_kernel(const int* __restrict__ deg, int* __restrict__ dbins, int n) {
  __shared__ int h[DBINS];
  int tid = threadIdx.x;
  if (tid < DBINS) h[tid] = 0;
  __syncthreads();
  for (int i = blockIdx.x * blockDim.x + tid; i < n; i += gridDim.x * blockDim.x)
    atomicAdd(&h[min(deg[i], DBINS - 1)], 1);
  __syncthreads();
  if (tid < DBINS) atomicAdd(&dbins[tid], h[tid]);
}

// descending base offsets: dbase[b] = sum_{b' > b} dbins[b']; dcur = copy
__global__ void deg_scan_kernel(const int* __restrict__ dbins, int* __restrict__ dcur) {
  __shared__ int tmp[DBINS];
  int tid = threadIdx.x;           // 256 threads
  int rb  = DBINS - 1 - tid;       // reversed order
  int v = dbins[rb];
  tmp[tid] = v;
  __syncthreads();
  for (int off = 1; off < DBINS; off <<= 1) {
    int t = (tid >= off) ? tmp[tid - off] : 0;
    __syncthreads();
    tmp[tid] += t;
    __syncthreads();
  }
  dcur[rb] = tmp[tid] - v;         // exclusive suffix-sum (descending layout)
}

__global__ void deg_scatter_kernel(const int* __restrict__ deg, int* __restrict__ dcur,
                                   int* __restrict__ rowperm, int n) {
  int i = blockIdx.x * blockDim.x + threadIdx.x;
  if (i < n) {
    int pos = atomicAdd(&dcur[min(deg[i], DBINS - 1)], 1);
    rowperm[pos] = i;
  }
}

// ---------------- dense GEMM: C[M,128] = A[M,K] @ W[K,128] ----------------
// m97-style 2-phase pipeline: BM=128, BN=128, BK=16, 256 threads, 8x8/thread.
// LDS staged by global_load_lds w16 (zero staging VGPRs); A-read conflict
// fixed by pre-swizzled global source + same XOR on LDS read (m173).

__device__ __forceinline__ void gload16(const float* src, float* dst_lds) {
  __builtin_amdgcn_global_load_lds(
      (const __attribute__((address_space(1))) void*)src,
      (__attribute__((address_space(3))) void*)dst_lds,
      16, 0, 0);
}

template<int K>
__global__ __launch_bounds__(256) void gemm_kernel(const float* __restrict__ A,
                                                   const float* __restrict__ W,
                                                   float* __restrict__ C, int M) {
  __shared__ __align__(16) float As[2][2048];
  __shared__ __align__(16) float Bs[2][2048];
  const int tid  = threadIdx.x;
  const int w    = tid >> 6;
  const int lane = tid & 63;
  const int r8   = tid >> 4;
  const int c8   = tid & 15;
  const int block_row = blockIdx.x * 128;

  float acc[2][2][4][4] = {};

  auto prefetch = [&](int t) {
    const int buf = t & 1;
    const int k0  = t * 16;
    #pragma unroll
    for (int j = 0; j < 2; ++j) {
      int s   = j * 256 + w * 64 + lane;
      int row = s >> 2;
      int q   = (s & 3) ^ ((row >> 2) & 3);
      int grow = block_row + row;
      if (grow >= M) grow = M - 1;
      gload16(A + (size_t)grow * K + k0 + q * 4,
              &As[buf][(j * 256 + w * 64) * 4]);
    }
    #pragma unroll
    for (int j = 0; j < 2; ++j) {
      int s = j * 256 + w * 64 + lane;
      int r = s >> 5, cq = s & 31;
      gload16(W + (size_t)(k0 + r) * 128 + cq * 4,
              &Bs[buf][(j * 256 + w * 64) * 4]);
    }
  };

  constexpr int NT = K / 16;
  prefetch(0);
  for (int t = 0; t < NT; ++t) {
    __syncthreads();
    if (t + 1 < NT) prefetch(t + 1);
    const float* as = As[t & 1];
    const float* bs = Bs[t & 1];
    #pragma unroll
    for (int q = 0; q < 4; ++q) {
      float av[2][4][4];
      #pragma unroll
      for (int rh = 0; rh < 2; ++rh)
        #pragma unroll
        for (int i = 0; i < 4; ++i) {
          int row = rh * 64 + r8 * 4 + i;
          float4 a = *(const float4*)&as[(row * 4 + (q ^ ((row >> 2) & 3))) * 4];
          av[rh][i][0] = a.x; av[rh][i][1] = a.y;
          av[rh][i][2] = a.z; av[rh][i][3] = a.w;
        }
      #pragma unroll
      for (int j = 0; j < 4; ++j) {
        int kk = q * 4 + j;
        float4 b0 = *(const float4*)&bs[(kk * 32 + c8) * 4];
        float4 b1 = *(const float4*)&bs[(kk * 32 + 16 + c8) * 4];
        #pragma unroll
        for (int rh = 0; rh < 2; ++rh)
          #pragma unroll
          for (int i = 0; i < 4; ++i) {
            float a = av[rh][i][j];
            acc[rh][0][i][0] += a * b0.x; acc[rh][0][i][1] += a * b0.y;
            acc[rh][0][i][2] += a * b0.z; acc[rh][0][i][3] += a * b0.w;
            acc[rh][1][i][0] += a * b1.x; acc[rh][1][i][1] += a * b1.y;
            acc[rh][1][i][2] += a * b1.z; acc[rh][1][i][3] += a * b1.w;
          }
      }
    }
  }

  #pragma unroll
  for (int rh = 0; rh < 2; ++rh)
    #pragma unroll
    for (int i = 0; i < 4; ++i) {
      int grow = block_row + rh * 64 + r8 * 4 + i;
      if (grow < M) {
        #pragma unroll
        for (int ch = 0; ch < 2; ++ch) {
          float4 v = make_float4(acc[rh][ch][i][0], acc[rh][ch][i][1],
                                 acc[rh][ch][i][2], acc[rh][ch][i][3]);
          *(float4*)&C[(size_t)grow * 128 + ch * 64 + c8 * 4] = v;
        }
      }
    }
}

// ---------------- SpMM + bias + ReLU ----------------
// TWO degree-matched rows per 64-lane wave (rowperm pairs equal-degree rows
// -> mdeg waste ~0). float4 gathers, unroll x16 -> 16 outstanding 512B
// gathers per wave.

__global__ void spmm_kernel(const float* __restrict__ support, const int* __restrict__ row_ptr,
                            const int2* __restrict__ ev, const int* __restrict__ rowperm,
                            const float* __restrict__ bias, float* __restrict__ out,
                            int n_nodes) {
  int wid   = blockIdx.x * (blockDim.x >> 6) + (threadIdx.x >> 6);
  int lane  = threadIdx.x & 63;
  int half  = lane >> 5;
  int flane = lane & 31;
  int pidx  = wid * 2 + half;
  bool rv   = pidx < n_nodes;
  int row   = rv ? rowperm[pidx] : 0;
  int beg = rv ? row_ptr[row]     : 0;
  int end = rv ? row_ptr[row + 1] : 0;
  int deg = rv ? (end - beg) : 0;
  int mdeg = max(__shfl(deg, 0), __shfl(deg, 32));   // wave-uniform

  float4 acc = make_float4(0.f, 0.f, 0.f, 0.f);
  const int sb = half * 32;

  for (int chunk = 0; chunk < mdeg; chunk += 32) {
    int idx = beg + chunk + flane;
    int2 ee = (idx < end) ? ev[idx] : make_int2(0, 0);
    int   cl = ee.x;
    float vl = __int_as_float(ee.y);
    int m = min(32, mdeg - chunk);
    int e = 0;
    for (; e + 16 <= m; e += 16) {
      int   c0 = __shfl(cl, sb + e + 0),  c1 = __shfl(cl, sb + e + 1);
      int   c2 = __shfl(cl, sb + e + 2),  c3 = __shfl(cl, sb + e + 3);
      int   c4 = __shfl(cl, sb + e + 4),  c5 = __shfl(cl, sb + e + 5);
      int   c6 = __shfl(cl, sb + e + 6),  c7 = __shfl(cl, sb + e + 7);
      int   c8 = __shfl(cl, sb + e + 8),  c9 = __shfl(cl, sb + e + 9);
      int   cA = __shfl(cl, sb + e + 10), cB = __shfl(cl, sb + e + 11);
      int   cC = __shfl(cl, sb + e + 12), cD = __shfl(cl, sb + e + 13);
      int   cE = __shfl(cl, sb + e + 14), cF = __shfl(cl, sb + e + 15);
      float v0 = __shfl(vl, sb + e + 0),  v1 = __shfl(vl, sb + e + 1);
      float v2 = __shfl(vl, sb + e + 2),  v3 = __shfl(vl, sb + e + 3);
      float v4 = __shfl(vl, sb + e + 4),  v5 = __shfl(vl, sb + e + 5);
      float v6 = __shfl(vl, sb + e + 6),  v7 = __shfl(vl, sb + e + 7);
      float v8 = __shfl(vl, sb + e + 8),  v9 = __shfl(vl, sb + e + 9);
      float vA = __shfl(vl, sb + e + 10), vB = __shfl(vl, sb + e + 11);
      float vC = __shfl(vl, sb + e + 12), vD = __shfl(vl, sb + e + 13);
      float vE = __shfl(vl, sb + e + 14), vF = __shfl(vl, sb + e + 15);
      float4 s0 = *(const float4*)&support[(size_t)c0 * 128 + flane * 4];
      float4 s1 = *(const float4*)&support[(size_t)c1 * 128 + flane * 4];
      float4 s2 = *(const float4*)&support[(size_t)c2 * 128 + flane * 4];
      float4 s3 = *(const float4*)&support[(size_t)c3 * 128 + flane * 4];
      float4 s4 = *(const float4*)&support[(size_t)c4 * 128 + flane * 4];
      float4 s5 = *(const float4*)&support[(size_t)c5 * 128 + flane * 4];
      float4 s6 = *(const float4*)&support[(size_t)c6 * 128 + flane * 4];
      float4 s7 = *(const float4*)&support[(size_t)c7 * 128 + flane * 4];
      float4 s8 = *(const float4*)&support[(size_t)c8 * 128 + flane * 4];
      float4 s9 = *(const float4*)&support[(size_t)c9 * 128 + flane * 4];
      float4 sA = *(const float4*)&support[(size_t)cA * 128 + flane * 4];
      float4 sB = *(const float4*)&support[(size_t)cB * 128 + flane * 4];
      float4 sC = *(const float4*)&support[(size_t)cC * 128 + flane * 4];
      float4 sD = *(const float4*)&support[(size_t)cD * 128 + flane * 4];
      float4 sE = *(const float4*)&support[(size_t)cE * 128 + flane * 4];
      float4 sF = *(const float4*)&support[(size_t)cF * 128 + flane * 4];
      acc.x += v0 * s0.x; acc.y += v0 * s0.y; acc.z += v0 * s0.z; acc.w += v0 * s0.w;
      acc.x += v1 * s1.x; acc.y += v1 * s1.y; acc.z += v1 * s1.z; acc.w += v1 * s1.w;
      acc.x += v2 * s2.x; acc.y += v2 * s2.y; acc.z += v2 * s2.z; acc.w += v2 * s2.w;
      acc.x += v3 * s3.x; acc.y += v3 * s3.y; acc.z += v3 * s3.z; acc.w += v3 * s3.w;
      acc.x += v4 * s4.x; acc.y += v4 * s4.y; acc.z += v4 * s4.z; acc.w += v4 * s4.w;
      acc.x += v5 * s5.x; acc.y += v5 * s5.y; acc.z += v5 * s5.z; acc.w += v5 * s5.w;
      acc.x += v6 * s6.x; acc.y += v6 * s6.y; acc.z += v6 * s6.z; acc.w += v6 * s6.w;
      acc.x += v7 * s7.x; acc.y += v7 * s7.y; acc.z += v7 * s7.z; acc.w += v7 * s7.w;
      acc.x += v8 * s8.x; acc.y += v8 * s8.y; acc.z += v8 * s8.z; acc.w += v8 * s8.w;
      acc.x += v9 * s9.x; acc.y += v9 * s9.y; acc.z += v9 * s9.z; acc.w += v9 * s9.w;
      acc.x += vA * sA.x; acc.y += vA * sA.y; acc.z += vA * sA.z; acc.w += vA * sA.w;
      acc.x += vB * sB.x; acc.y += vB * sB.y; acc.z += vB * sB.z; acc.w += vB * sB.w;
      acc.x += vC * sC.x; acc.y += vC * sC.y; acc.z += vC * sC.z; acc.w += vC * sC.w;
      acc.x += vD * sD.x; acc.y += vD * sD.y; acc.z += vD * sD.z; acc.w += vD * sD.w;
      acc.x += vE * sE.x; acc.y += vE * sE.y; acc.z += vE * sE.z; acc.w += vE * sE.w;
      acc.x += vF * sF.x; acc.y += vF * sF.y; acc.z += vF * sF.z; acc.w += vF * sF.w;
    }
    for (; e + 8 <= m; e += 8) {
      int   c0 = __shfl(cl, sb + e + 0), c1 = __shfl(cl, sb + e + 1);
      int   c2 = __shfl(cl, sb + e + 2), c3 = __shfl(cl, sb + e + 3);
      int   c4 = __shfl(cl, sb + e + 4), c5 = __shfl(cl, sb + e + 5);
      int   c6 = __shfl(cl, sb + e + 6), c7 = __shfl(cl, sb + e + 7);
      float v0 = __shfl(vl, sb + e + 0), v1 = __shfl(vl, sb + e + 1);
      float v2 = __shfl(vl, sb + e + 2), v3 = __shfl(vl, sb + e + 3);
      float v4 = __shfl(vl, sb + e + 4), v5 = __shfl(vl, sb + e + 5);
      float v6 = __shfl(vl, sb + e + 6), v7 = __shfl(vl, sb + e + 7);
      float4 s0 = *(const float4*)&support[(size_t)c0 * 128 + flane * 4];
      float4 s1 = *(const float4*)&support[(size_t)c1 * 128 + flane * 4];
      float4 s2 = *(const float4*)&support[(size_t)c2 * 128 + flane * 4];
      float4 s3 = *(const float4*)&support[(size_t)c3 * 128 + flane * 4];
      float4 s4 = *(const float4*)&support[(size_t)c4 * 128 + flane * 4];
      float4 s5 = *(const float4*)&support[(size_t)c5 * 128 + flane * 4];
      float4 s6 = *(const float4*)&support[(size_t)c6 * 128 + flane * 4];
      float4 s7 = *(const float4*)&support[(size_t)c7 * 128 + flane * 4];
      acc.x += v0 * s0.x; acc.y += v0 * s0.y; acc.z += v0 * s0.z; acc.w += v0 * s0.w;
      acc.x += v1 * s1.x; acc.y += v1 * s1.y; acc.z += v1 * s1.z; acc.w += v1 * s1.w;
      acc.x += v2 * s2.x; acc.y += v2 * s2.y; acc.z += v2 * s2.z; acc.w += v2 * s2.w;
      acc.x += v3 * s3.x; acc.y += v3 * s3.y; acc.z += v3 * s3.z; acc.w += v3 * s3.w;
      acc.x += v4 * s4.x; acc.y += v4 * s4.y; acc.z += v4 * s4.z; acc.w += v4 * s4.w;
      acc.x += v5 * s5.x; acc.y += v5 * s5.y; acc.z += v5 * s5.z; acc.w += v5 * s5.w;
      acc.x += v6 * s6.x; acc.y += v6 * s6.y; acc.z += v6 * s6.z; acc.w += v6 * s6.w;
      acc.x += v7 * s7.x; acc.y += v7 * s7.y; acc.z += v7 * s7.z; acc.w += v7 * s7.w;
    }
    for (; e < m; ++e) {
      int   ce = __shfl(cl, sb + e);
      float ve = __shfl(vl, sb + e);
      float4 s = *(const float4*)&support[(size_t)ce * 128 + flane * 4];
      acc.x += ve * s.x; acc.y += ve * s.y; acc.z += ve * s.z; acc.w += ve * s.w;
    }
  }
  if (rv) {
    float4 b = *(const float4*)&bias[flane * 4];
    float4 o = make_float4(fmaxf(acc.x + b.x, 0.f), fmaxf(acc.y + b.y, 0.f),
                           fmaxf(acc.z + b.z, 0.f), fmaxf(acc.w + b.w, 0.f));
    *(float4*)&out[(size_t)row * 128 + flane * 4] = o;
  }
}

// ---------------- launch ----------------

extern "C" void kernel_launch(void* const* d_in, const int* in_sizes, int n_in,
                              void* d_out, int out_size, void* d_ws, size_t ws_size,
                              hipStream_t stream) {
  const float* x    = (const float*)d_in[0];
  const int*   erow = (const int*)d_in[1];
  const int*   ecol = (const int*)d_in[2];
  const float* evl  = (const float*)d_in[3];
  const float* W1   = (const float*)d_in[4];
  const float* b1   = (const float*)d_in[5];
  const float* W2   = (const float*)d_in[6];
  const float* b2   = (const float*)d_in[7];
  int n_nodes = in_sizes[0] / NFEAT;
  int n_edges = in_sizes[1];
  float* out = (float*)d_out;

  char* ws = (char*)d_ws;
  size_t off = 0;
  auto alloc = [&](size_t bytes) -> void* {
    void* p = ws + off;
    off += bytes;
    off = (off + 255) & ~(size_t)255;
    return p;
  };
  float* support = (float*)alloc((size_t)n_nodes * NHID * sizeof(float));
  int*   cnt     = (int*)alloc((size_t)n_nodes * sizeof(int));
  int*   row_ptr = (int*)alloc(((size_t)n_nodes + 1) * sizeof(int));
  int*   rank    = (int*)alloc((size_t)n_edges * sizeof(int));
  int2*  ev_s    = (int2*)alloc((size_t)n_edges * sizeof(int2));
  int*   rowperm = (int*)alloc((size_t)n_nodes * sizeof(int));
  int*   dbins   = (int*)alloc(DBINS * sizeof(int));
  int*   dcur    = (int*)alloc(DBINS * sizeof(int));
  int nb = (n_nodes + SCAN_B - 1) / SCAN_B;
  int*   bsum    = (int*)alloc((size_t)(nb + 1) * sizeof(int));

  // CSR build + degree-sorted row perm (shared by all 5 layers)
  hipMemsetAsync(cnt, 0, (size_t)n_nodes * sizeof(int), stream);
  hipMemsetAsync(dbins, 0, DBINS * sizeof(int), stream);
  hist_kernel<<<(n_edges + 255) / 256, 256, 0, stream>>>(erow, cnt, rank, n_edges);
  scan1_kernel<<<nb, 1024, 0, stream>>>(cnt, row_ptr, bsum, n_nodes);
  scan2_kernel<<<1, 64, 0, stream>>>(bsum, nb);
  scan3_kernel<<<(n_nodes + 255) / 256, 256, 0, stream>>>(row_ptr, bsum, n_nodes, nb);
  scatter_kernel<<<(n_edges + 255) / 256, 256, 0, stream>>>(erow, ecol, evl, rank,
                                                            row_ptr, ev_s, n_edges);
  deg_hist_kernel<<<64, 256, 0, stream>>>(cnt, dbins, n_nodes);
  deg_scan_kernel<<<1, DBINS, 0, stream>>>(dbins, dcur);
  deg_scatter_kernel<<<(n_nodes + 255) / 256, 256, 0, stream>>>(cnt, dcur, rowperm, n_nodes);

  int gblocks = (n_nodes + 127) / 128;
  int sblocks = (n_nodes + 7) / 8;   // 4 waves/block x 2 rows/wave

  gemm_kernel<NFEAT><<<gblocks, 256, 0, stream>>>(x, W1, support, n_nodes);
  spmm_kernel<<<sblocks, 256, 0, stream>>>(support, row_ptr, ev_s, rowperm, b1, out, n_nodes);

  for (int l = 0; l < 4; ++l) {
    gemm_kernel<NHID><<<gblocks, 256, 0, stream>>>(out, W2, support, n_nodes);
    spmm_kernel<<<sblocks, 256, 0, stream>>>(support, row_ptr, ev_s, rowperm, b2, out, n_nodes);
  }
}

// Round 10
// 967.782 us; speedup vs baseline: 1.3093x; 1.3093x over previous
//
#include <hip/hip_runtime.h>

constexpr int NFEAT = 256;
constexpr int NHID  = 128;
constexpr int SCAN_B = 4096;   // elements per scan block (1024 threads x 4)

// ---------------- CSR build ----------------
// hist captures each edge's within-row rank from the atomicAdd return value;
// scatter then needs NO atomic: p = row_ptr[row] + rank (unique by constr.)

__global__ void hist_kernel(const int* __restrict__ rows, int* __restrict__ cnt,
                            int* __restrict__ rank, int n) {
  int i = blockIdx.x * blockDim.x + threadIdx.x;
  if (i < n) rank[i] = atomicAdd(&cnt[rows[i]], 1);
}

__global__ void scan1_kernel(const int* __restrict__ cnt, int* __restrict__ part,
                             int* __restrict__ bsum, int n) {
  __shared__ int tmp[1024];
  int tid = threadIdx.x;
  int base = blockIdx.x * SCAN_B + tid * 4;
  int4 v = make_int4(0, 0, 0, 0);
  if (base + 4 <= n) {
    v = *(const int4*)&cnt[base];
  } else {
    if (base + 0 < n) v.x = cnt[base + 0];
    if (base + 1 < n) v.y = cnt[base + 1];
    if (base + 2 < n) v.z = cnt[base + 2];
    if (base + 3 < n) v.w = cnt[base + 3];
  }
  int s = v.x + v.y + v.z + v.w;
  tmp[tid] = s;
  __syncthreads();
  for (int off = 1; off < 1024; off <<= 1) {
    int t = (tid >= off) ? tmp[tid - off] : 0;
    __syncthreads();
    tmp[tid] += t;
    __syncthreads();
  }
  int excl = tmp[tid] - s;
  if (base + 0 < n) part[base + 0] = excl;
  if (base + 1 < n) part[base + 1] = excl + v.x;
  if (base + 2 < n) part[base + 2] = excl + v.x + v.y;
  if (base + 3 < n) part[base + 3] = excl + v.x + v.y + v.z;
  if (tid == 1023) bsum[blockIdx.x] = tmp[1023];
}

__global__ void scan2_kernel(int* __restrict__ bsum, int nb) {
  if (threadIdx.x == 0 && blockIdx.x == 0) {
    int run = 0;
    for (int i = 0; i < nb; ++i) { int t = bsum[i]; bsum[i] = run; run += t; }
    bsum[nb] = run;
  }
}

__global__ void scan3_kernel(int* __restrict__ row_ptr, const int* __restrict__ bsum,
                             int n, int nb) {
  int i = blockIdx.x * blockDim.x + threadIdx.x;
  if (i < n) row_ptr[i] += bsum[i / SCAN_B];
  if (i == 0) row_ptr[n] = bsum[nb];
}

// atomic-free scatter: coalesced reads, 4B L2-hot row_ptr gather, one
// independent random 8B write per edge.
__global__ void scatter_kernel(const int* __restrict__ rows, const int* __restrict__ cols,
                               const float* __restrict__ vals, const int* __restrict__ rank,
                               const int* __restrict__ row_ptr, int2* __restrict__ ev_s, int n) {
  int i = blockIdx.x * blockDim.x + threadIdx.x;
  if (i < n) {
    int p = row_ptr[rows[i]] + rank[i];
    ev_s[p] = make_int2(cols[i], __float_as_int(vals[i]));
  }
}

// ---------------- dense GEMM: C[M,128] = A[M,K] @ W[K,128] ----------------
// m97-style 2-phase pipeline: BM=128, BN=128, BK=16, 256 threads, 8x8/thread.
// LDS staged by global_load_lds w16 (zero staging VGPRs); A-read conflict
// fixed by pre-swizzled global source + same XOR on LDS read (m173).

__device__ __forceinline__ void gload16(const float* src, float* dst_lds) {
  __builtin_amdgcn_global_load_lds(
      (const __attribute__((address_space(1))) void*)src,
      (__attribute__((address_space(3))) void*)dst_lds,
      16, 0, 0);
}

template<int K>
__global__ __launch_bounds__(256) void gemm_kernel(const float* __restrict__ A,
                                                   const float* __restrict__ W,
                                                   float* __restrict__ C, int M) {
  __shared__ __align__(16) float As[2][2048];
  __shared__ __align__(16) float Bs[2][2048];
  const int tid  = threadIdx.x;
  const int w    = tid >> 6;
  const int lane = tid & 63;
  const int r8   = tid >> 4;
  const int c8   = tid & 15;
  const int block_row = blockIdx.x * 128;

  float acc[2][2][4][4] = {};

  auto prefetch = [&](int t) {
    const int buf = t & 1;
    const int k0  = t * 16;
    #pragma unroll
    for (int j = 0; j < 2; ++j) {
      int s   = j * 256 + w * 64 + lane;
      int row = s >> 2;
      int q   = (s & 3) ^ ((row >> 2) & 3);
      int grow = block_row + row;
      if (grow >= M) grow = M - 1;
      gload16(A + (size_t)grow * K + k0 + q * 4,
              &As[buf][(j * 256 + w * 64) * 4]);
    }
    #pragma unroll
    for (int j = 0; j < 2; ++j) {
      int s = j * 256 + w * 64 + lane;
      int r = s >> 5, cq = s & 31;
      gload16(W + (size_t)(k0 + r) * 128 + cq * 4,
              &Bs[buf][(j * 256 + w * 64) * 4]);
    }
  };

  constexpr int NT = K / 16;
  prefetch(0);
  for (int t = 0; t < NT; ++t) {
    __syncthreads();
    if (t + 1 < NT) prefetch(t + 1);
    const float* as = As[t & 1];
    const float* bs = Bs[t & 1];
    #pragma unroll
    for (int q = 0; q < 4; ++q) {
      float av[2][4][4];
      #pragma unroll
      for (int rh = 0; rh < 2; ++rh)
        #pragma unroll
        for (int i = 0; i < 4; ++i) {
          int row = rh * 64 + r8 * 4 + i;
          float4 a = *(const float4*)&as[(row * 4 + (q ^ ((row >> 2) & 3))) * 4];
          av[rh][i][0] = a.x; av[rh][i][1] = a.y;
          av[rh][i][2] = a.z; av[rh][i][3] = a.w;
        }
      #pragma unroll
      for (int j = 0; j < 4; ++j) {
        int kk = q * 4 + j;
        float4 b0 = *(const float4*)&bs[(kk * 32 + c8) * 4];
        float4 b1 = *(const float4*)&bs[(kk * 32 + 16 + c8) * 4];
        #pragma unroll
        for (int rh = 0; rh < 2; ++rh)
          #pragma unroll
          for (int i = 0; i < 4; ++i) {
            float a = av[rh][i][j];
            acc[rh][0][i][0] += a * b0.x; acc[rh][0][i][1] += a * b0.y;
            acc[rh][0][i][2] += a * b0.z; acc[rh][0][i][3] += a * b0.w;
            acc[rh][1][i][0] += a * b1.x; acc[rh][1][i][1] += a * b1.y;
            acc[rh][1][i][2] += a * b1.z; acc[rh][1][i][3] += a * b1.w;
          }
      }
    }
  }

  #pragma unroll
  for (int rh = 0; rh < 2; ++rh)
    #pragma unroll
    for (int i = 0; i < 4; ++i) {
      int grow = block_row + rh * 64 + r8 * 4 + i;
      if (grow < M) {
        #pragma unroll
        for (int ch = 0; ch < 2; ++ch) {
          float4 v = make_float4(acc[rh][ch][i][0], acc[rh][ch][i][1],
                                 acc[rh][ch][i][2], acc[rh][ch][i][3]);
          *(float4*)&C[(size_t)grow * 128 + ch * 64 + c8 * 4] = v;
        }
      }
    }
}

// ---------------- SpMM + bias + ReLU ----------------
// TWO rows per 64-lane wave (lanes 0-31 -> r0, 32-63 -> r1), float4 gathers,
// unroll x16 -> 16 outstanding 512B gathers per wave. 512-thread blocks
// (8 waves, 16 rows) so 4 blocks/CU = 32 waves = 100% occupancy.

__global__ __launch_bounds__(512) void spmm_kernel(
    const float* __restrict__ support, const int* __restrict__ row_ptr,
    const int2* __restrict__ ev, const float* __restrict__ bias,
    float* __restrict__ out, int n_nodes) {
  int wid   = blockIdx.x * (blockDim.x >> 6) + (threadIdx.x >> 6);
  int lane  = threadIdx.x & 63;
  int half  = lane >> 5;
  int flane = lane & 31;
  int row   = wid * 2 + half;
  bool rv   = row < n_nodes;
  int beg = rv ? row_ptr[row]     : 0;
  int end = rv ? row_ptr[row + 1] : 0;
  int deg = rv ? (end - beg) : 0;
  int mdeg = max(__shfl(deg, 0), __shfl(deg, 32));   // wave-uniform

  float4 acc = make_float4(0.f, 0.f, 0.f, 0.f);
  const int sb = half * 32;

  for (int chunk = 0; chunk < mdeg; chunk += 32) {
    int idx = beg + chunk + flane;
    int2 ee = (idx < end) ? ev[idx] : make_int2(0, 0);
    int   cl = ee.x;
    float vl = __int_as_float(ee.y);
    int m = min(32, mdeg - chunk);
    int e = 0;
    for (; e + 16 <= m; e += 16) {
      int   c0 = __shfl(cl, sb + e + 0),  c1 = __shfl(cl, sb + e + 1);
      int   c2 = __shfl(cl, sb + e + 2),  c3 = __shfl(cl, sb + e + 3);
      int   c4 = __shfl(cl, sb + e + 4),  c5 = __shfl(cl, sb + e + 5);
      int   c6 = __shfl(cl, sb + e + 6),  c7 = __shfl(cl, sb + e + 7);
      int   c8 = __shfl(cl, sb + e + 8),  c9 = __shfl(cl, sb + e + 9);
      int   cA = __shfl(cl, sb + e + 10), cB = __shfl(cl, sb + e + 11);
      int   cC = __shfl(cl, sb + e + 12), cD = __shfl(cl, sb + e + 13);
      int   cE = __shfl(cl, sb + e + 14), cF = __shfl(cl, sb + e + 15);
      float v0 = __shfl(vl, sb + e + 0),  v1 = __shfl(vl, sb + e + 1);
      float v2 = __shfl(vl, sb + e + 2),  v3 = __shfl(vl, sb + e + 3);
      float v4 = __shfl(vl, sb + e + 4),  v5 = __shfl(vl, sb + e + 5);
      float v6 = __shfl(vl, sb + e + 6),  v7 = __shfl(vl, sb + e + 7);
      float v8 = __shfl(vl, sb + e + 8),  v9 = __shfl(vl, sb + e + 9);
      float vA = __shfl(vl, sb + e + 10), vB = __shfl(vl, sb + e + 11);
      float vC = __shfl(vl, sb + e + 12), vD = __shfl(vl, sb + e + 13);
      float vE = __shfl(vl, sb + e + 14), vF = __shfl(vl, sb + e + 15);
      float4 s0 = *(const float4*)&support[(size_t)c0 * 128 + flane * 4];
      float4 s1 = *(const float4*)&support[(size_t)c1 * 128 + flane * 4];
      float4 s2 = *(const float4*)&support[(size_t)c2 * 128 + flane * 4];
      float4 s3 = *(const float4*)&support[(size_t)c3 * 128 + flane * 4];
      float4 s4 = *(const float4*)&support[(size_t)c4 * 128 + flane * 4];
      float4 s5 = *(const float4*)&support[(size_t)c5 * 128 + flane * 4];
      float4 s6 = *(const float4*)&support[(size_t)c6 * 128 + flane * 4];
      float4 s7 = *(const float4*)&support[(size_t)c7 * 128 + flane * 4];
      float4 s8 = *(const float4*)&support[(size_t)c8 * 128 + flane * 4];
      float4 s9 = *(const float4*)&support[(size_t)c9 * 128 + flane * 4];
      float4 sA = *(const float4*)&support[(size_t)cA * 128 + flane * 4];
      float4 sB = *(const float4*)&support[(size_t)cB * 128 + flane * 4];
      float4 sC = *(const float4*)&support[(size_t)cC * 128 + flane * 4];
      float4 sD = *(const float4*)&support[(size_t)cD * 128 + flane * 4];
      float4 sE = *(const float4*)&support[(size_t)cE * 128 + flane * 4];
      float4 sF = *(const float4*)&support[(size_t)cF * 128 + flane * 4];
      acc.x += v0 * s0.x; acc.y += v0 * s0.y; acc.z += v0 * s0.z; acc.w += v0 * s0.w;
      acc.x += v1 * s1.x; acc.y += v1 * s1.y; acc.z += v1 * s1.z; acc.w += v1 * s1.w;
      acc.x += v2 * s2.x; acc.y += v2 * s2.y; acc.z += v2 * s2.z; acc.w += v2 * s2.w;
      acc.x += v3 * s3.x; acc.y += v3 * s3.y; acc.z += v3 * s3.z; acc.w += v3 * s3.w;
      acc.x += v4 * s4.x; acc.y += v4 * s4.y; acc.z += v4 * s4.z; acc.w += v4 * s4.w;
      acc.x += v5 * s5.x; acc.y += v5 * s5.y; acc.z += v5 * s5.z; acc.w += v5 * s5.w;
      acc.x += v6 * s6.x; acc.y += v6 * s6.y; acc.z += v6 * s6.z; acc.w += v6 * s6.w;
      acc.x += v7 * s7.x; acc.y += v7 * s7.y; acc.z += v7 * s7.z; acc.w += v7 * s7.w;
      acc.x += v8 * s8.x; acc.y += v8 * s8.y; acc.z += v8 * s8.z; acc.w += v8 * s8.w;
      acc.x += v9 * s9.x; acc.y += v9 * s9.y; acc.z += v9 * s9.z; acc.w += v9 * s9.w;
      acc.x += vA * sA.x; acc.y += vA * sA.y; acc.z += vA * sA.z; acc.w += vA * sA.w;
      acc.x += vB * sB.x; acc.y += vB * sB.y; acc.z += vB * sB.z; acc.w += vB * sB.w;
      acc.x += vC * sC.x; acc.y += vC * sC.y; acc.z += vC * sC.z; acc.w += vC * sC.w;
      acc.x += vD * sD.x; acc.y += vD * sD.y; acc.z += vD * sD.z; acc.w += vD * sD.w;
      acc.x += vE * sE.x; acc.y += vE * sE.y; acc.z += vE * sE.z; acc.w += vE * sE.w;
      acc.x += vF * sF.x; acc.y += vF * sF.y; acc.z += vF * sF.z; acc.w += vF * sF.w;
    }
    for (; e + 8 <= m; e += 8) {
      int   c0 = __shfl(cl, sb + e + 0), c1 = __shfl(cl, sb + e + 1);
      int   c2 = __shfl(cl, sb + e + 2), c3 = __shfl(cl, sb + e + 3);
      int   c4 = __shfl(cl, sb + e + 4), c5 = __shfl(cl, sb + e + 5);
      int   c6 = __shfl(cl, sb + e + 6), c7 = __shfl(cl, sb + e + 7);
      float v0 = __shfl(vl, sb + e + 0), v1 = __shfl(vl, sb + e + 1);
      float v2 = __shfl(vl, sb + e + 2), v3 = __shfl(vl, sb + e + 3);
      float v4 = __shfl(vl, sb + e + 4), v5 = __shfl(vl, sb + e + 5);
      float v6 = __shfl(vl, sb + e + 6), v7 = __shfl(vl, sb + e + 7);
      float4 s0 = *(const float4*)&support[(size_t)c0 * 128 + flane * 4];
      float4 s1 = *(const float4*)&support[(size_t)c1 * 128 + flane * 4];
      float4 s2 = *(const float4*)&support[(size_t)c2 * 128 + flane * 4];
      float4 s3 = *(const float4*)&support[(size_t)c3 * 128 + flane * 4];
      float4 s4 = *(const float4*)&support[(size_t)c4 * 128 + flane * 4];
      float4 s5 = *(const float4*)&support[(size_t)c5 * 128 + flane * 4];
      float4 s6 = *(const float4*)&support[(size_t)c6 * 128 + flane * 4];
      float4 s7 = *(const float4*)&support[(size_t)c7 * 128 + flane * 4];
      acc.x += v0 * s0.x; acc.y += v0 * s0.y; acc.z += v0 * s0.z; acc.w += v0 * s0.w;
      acc.x += v1 * s1.x; acc.y += v1 * s1.y; acc.z += v1 * s1.z; acc.w += v1 * s1.w;
      acc.x += v2 * s2.x; acc.y += v2 * s2.y; acc.z += v2 * s2.z; acc.w += v2 * s2.w;
      acc.x += v3 * s3.x; acc.y += v3 * s3.y; acc.z += v3 * s3.z; acc.w += v3 * s3.w;
      acc.x += v4 * s4.x; acc.y += v4 * s4.y; acc.z += v4 * s4.z; acc.w += v4 * s4.w;
      acc.x += v5 * s5.x; acc.y += v5 * s5.y; acc.z += v5 * s5.z; acc.w += v5 * s5.w;
      acc.x += v6 * s6.x; acc.y += v6 * s6.y; acc.z += v6 * s6.z; acc.w += v6 * s6.w;
      acc.x += v7 * s7.x; acc.y += v7 * s7.y; acc.z += v7 * s7.z; acc.w += v7 * s7.w;
    }
    for (; e < m; ++e) {
      int   ce = __shfl(cl, sb + e);
      float ve = __shfl(vl, sb + e);
      float4 s = *(const float4*)&support[(size_t)ce * 128 + flane * 4];
      acc.x += ve * s.x; acc.y += ve * s.y; acc.z += ve * s.z; acc.w += ve * s.w;
    }
  }
  if (rv) {
    float4 b = *(const float4*)&bias[flane * 4];
    float4 o = make_float4(fmaxf(acc.x + b.x, 0.f), fmaxf(acc.y + b.y, 0.f),
                           fmaxf(acc.z + b.z, 0.f), fmaxf(acc.w + b.w, 0.f));
    *(float4*)&out[(size_t)row * 128 + flane * 4] = o;
  }
}

// ---------------- launch ----------------

extern "C" void kernel_launch(void* const* d_in, const int* in_sizes, int n_in,
                              void* d_out, int out_size, void* d_ws, size_t ws_size,
                              hipStream_t stream) {
  const float* x    = (const float*)d_in[0];
  const int*   erow = (const int*)d_in[1];
  const int*   ecol = (const int*)d_in[2];
  const float* evl  = (const float*)d_in[3];
  const float* W1   = (const float*)d_in[4];
  const float* b1   = (const float*)d_in[5];
  const float* W2   = (const float*)d_in[6];
  const float* b2   = (const float*)d_in[7];
  int n_nodes = in_sizes[0] / NFEAT;
  int n_edges = in_sizes[1];
  float* out = (float*)d_out;

  char* ws = (char*)d_ws;
  size_t off = 0;
  auto alloc = [&](size_t bytes) -> void* {
    void* p = ws + off;
    off += bytes;
    off = (off + 255) & ~(size_t)255;
    return p;
  };
  float* support = (float*)alloc((size_t)n_nodes * NHID * sizeof(float));
  int*   cnt     = (int*)alloc((size_t)n_nodes * sizeof(int));
  int*   row_ptr = (int*)alloc(((size_t)n_nodes + 1) * sizeof(int));
  int*   rank    = (int*)alloc((size_t)n_edges * sizeof(int));
  int2*  ev_s    = (int2*)alloc((size_t)n_edges * sizeof(int2));
  int nb = (n_nodes + SCAN_B - 1) / SCAN_B;
  int*   bsum    = (int*)alloc((size_t)(nb + 1) * sizeof(int));

  // CSR build (shared by all 5 layers)
  hipMemsetAsync(cnt, 0, (size_t)n_nodes * sizeof(int), stream);
  hist_kernel<<<(n_edges + 255) / 256, 256, 0, stream>>>(erow, cnt, rank, n_edges);
  scan1_kernel<<<nb, 1024, 0, stream>>>(cnt, row_ptr, bsum, n_nodes);
  scan2_kernel<<<1, 64, 0, stream>>>(bsum, nb);
  scan3_kernel<<<(n_nodes + 255) / 256, 256, 0, stream>>>(row_ptr, bsum, n_nodes, nb);
  scatter_kernel<<<(n_edges + 255) / 256, 256, 0, stream>>>(erow, ecol, evl, rank,
                                                            row_ptr, ev_s, n_edges);

  int gblocks = (n_nodes + 127) / 128;
  int sblocks = (n_nodes + 15) / 16;   // 8 waves/block x 2 rows/wave

  gemm_kernel<NFEAT><<<gblocks, 256, 0, stream>>>(x, W1, support, n_nodes);
  spmm_kernel<<<sblocks, 512, 0, stream>>>(support, row_ptr, ev_s, b1, out, n_nodes);

  for (int l = 0; l < 4; ++l) {
    gemm_kernel<NHID><<<gblocks, 256, 0, stream>>>(out, W2, support, n_nodes);
    spmm_kernel<<<sblocks, 512, 0, stream>>>(support, row_ptr, ev_s, b2, out, n_nodes);
  }
}